// Round 12
// baseline (81.842 us; speedup 1.0000x reference)
//
#include <hip/hip_runtime.h>
#include <math.h>

#define S 76
#define A 3
#define CH 85            // 5 + 80
#define MAXGT 150
#define CPB (S * S * A)              // 17328 cells per batch
#define FPB (CPB * CH)               // 1472880 floats per batch
#define BATCH 16
#define BLK 256
#define WPB 4
#define TILE 192                     // cells per full block (48/wave, exact)
#define F4_W 1020                    // float4 per wave = 48*85/4
#define ROUNDS 16                    // 15 full rounds + 1 partial (60 lanes)
#define DEPTH 4                      // DMA ring slots
#define GX ((CPB + TILE - 1) / TILE) // 91 (last block: 48 cells)
#define NBLK (GX * BATCH)            // 1456

typedef float fx4 __attribute__((ext_vector_type(4)));

__device__ __forceinline__ float frcp(float x) { return __builtin_amdgcn_rcpf(x); }
__device__ __forceinline__ float sigmoidf_(float x) { return frcp(1.f + __expf(-x)); }
// bce_with_logits(x,y) = ln(1+e^x) - x*y   (safe for |x| < ~80)
__device__ __forceinline__ float bcef(float x, float y) {
    const float t  = __builtin_amdgcn_exp2f(x * 1.44269504f);
    const float lg = __builtin_amdgcn_logf(1.f + t);            // log2(1+e^x)
    return __builtin_fmaf(0.69314718f, lg, -x * y);
}

// counted vmem wait; "memory" clobber orders all memory ops
template<int N>
__device__ __forceinline__ void vmwait() {
    asm volatile("s_waitcnt vmcnt(%0)" :: "i"(N) : "memory");
    __builtin_amdgcn_sched_barrier(0);
}
// direct global->LDS DMA, 16B per lane; LDS dest = wave-uniform base + lane*16
__device__ __forceinline__ void gl_lds16(const float* g, void* l) {
    __builtin_amdgcn_global_load_lds(
        (const __attribute__((address_space(1))) void*)g,
        (__attribute__((address_space(3))) void*)l, 16, 0, 0);
}

// One block = 192 cells of one batch. Stream the contiguous conv+label range
// via a DMA-ring pipeline (the ONLY bulk global traffic); extract the 5+5
// header channels into LDS as a side-effect; then geo losses purely from LDS.
__global__ __launch_bounds__(BLK) void yolo_unified_kernel(
    const float* __restrict__ conv, const float* __restrict__ label,
    const float* __restrict__ bboxes, float* __restrict__ part)
{
    __shared__ fx4   ring_c[WPB * DEPTH * 64];   // 16 KB
    __shared__ fx4   ring_l[WPB * DEPTH * 64];   // 16 KB
    __shared__ float s_ch[TILE][5];              // conv header
    __shared__ float s_lh[TILE][5];              // label header
    __shared__ float s_resp[TILE];
    __shared__ fx4   s_box[MAXGT];               // 3*x1, y1, 3*x2, y2
    __shared__ float s_ba[MAXGT];
    __shared__ float sred[3][WPB];

    const int b    = blockIdx.y;
    const int tile = blockIdx.x;
    const int tid  = threadIdx.x;
    const int w    = tid >> 6;
    const int lane = tid & 63;
    const int base_cell = tile * TILE;
    const int ncells = min(TILE, CPB - base_cell);

    const size_t eb = (size_t)b * FPB + (size_t)base_cell * CH;
    const float* cvb = conv  + eb;
    const float* lbb = label + eb;

    // ---- phase 0: boxes + resp -> LDS (all drained at the barrier) ----
    if (tid < MAXGT) {
        const float4 bx = *(const float4*)(bboxes + (size_t)b * (MAXGT * 4) + tid * 4);
        const float hw = bx.z * 0.5f, hh = bx.w * 0.5f;
        fx4 v; v.x = 3.f * (bx.x - hw); v.y = bx.y - hh;
        v.z = 3.f * (bx.x + hw); v.w = bx.y + hh;
        s_box[tid] = v;
        s_ba[tid]  = bx.z * bx.w;
    }
    for (int c = tid; c < ncells; c += BLK)
        s_resp[c] = lbb[(size_t)c * CH + 4];
    __syncthreads();                 // vmcnt drains to 0 -> clean counted region

    float p_sum = 0.f;

    if (ncells == TILE) {
        // ---- DMA-ring stream: wave w owns f4 range [w*1020, w*1020+1020) ----
        const float* pc = cvb + ((size_t)w * F4_W + (size_t)lane) * 4;
        const float* pl = lbb + ((size_t)w * F4_W + (size_t)lane) * 4;

        #define SLOT(R) ((w * DEPTH + ((R) & 3)) * 64)
        #define ISSUE(R)                                                       \
            gl_lds16(pc + (size_t)(R) * 256, &ring_c[SLOT(R)]);                \
            gl_lds16(pl + (size_t)(R) * 256, &ring_l[SLOT(R)]);

        ISSUE(0) ISSUE(1) ISSUE(2) ISSUE(3)          // 8 loads in flight
        fx4 rc[2], rl[2];
        vmwait<6>();                                  // slot 0 complete
        rc[0] = ring_c[SLOT(0) + lane];
        rl[0] = ring_l[SLOT(0) + lane];
        __builtin_amdgcn_sched_barrier(0);

        // round R: vmwait -> pong ds_read (slot R+1) -> compute ping (headers
        // extracted via conditional ds_writes) -> lgkmcnt(0) (free, issued
        // ~200cy earlier) -> DMA refill slot R.
        #define STEPX(R, W_)                                                    \
        {                                                                       \
            if ((R) + 1 < ROUNDS) {                                             \
                vmwait<W_>();                                                   \
                rc[((R) + 1) & 1] = ring_c[SLOT((R) + 1) + lane];               \
                rl[((R) + 1) & 1] = ring_l[SLOT((R) + 1) + lane];               \
                __builtin_amdgcn_sched_barrier(0);                              \
            }                                                                   \
            if ((R) < ROUNDS - 1 || lane < 60) {                                \
                const fx4 cc = rc[(R) & 1];                                     \
                const fx4 lc = rl[(R) & 1];                                     \
                const unsigned e0 = 4u * (unsigned)(w * F4_W + (R) * 64 + lane);\
                const unsigned c0 = e0 / 85u;                                   \
                const unsigned r0 = e0 - 85u * c0;                              \
                const float rsp = s_resp[c0];                                   \
                const float cxx[4] = {cc.x, cc.y, cc.z, cc.w};                  \
                const float lxx[4] = {lc.x, lc.y, lc.z, lc.w};                  \
                float s_ = 0.f;                                                 \
                _Pragma("unroll")                                               \
                for (int k = 0; k < 4; ++k) {                                   \
                    const unsigned rr = r0 + (unsigned)k;   /* [0,87] */        \
                    const float bv = bcef(cxx[k], lxx[k]);                      \
                    s_ += ((rr - 5u) < 80u) ? bv : 0.f;                         \
                    if (rr < 5u)       { s_ch[c0][rr] = cxx[k];                 \
                                         s_lh[c0][rr] = lxx[k]; }               \
                    else if (rr >= 85u){ s_ch[c0 + 1][rr - 85u] = cxx[k];       \
                                         s_lh[c0 + 1][rr - 85u] = lxx[k]; }     \
                }                                                               \
                p_sum = __builtin_fmaf(rsp, s_, p_sum);                         \
            }                                                                   \
            if ((R) < ROUNDS - 1) {                                             \
                asm volatile("s_waitcnt lgkmcnt(0)" ::: "memory");              \
                __builtin_amdgcn_sched_barrier(0);                              \
                if ((R) + DEPTH < ROUNDS) { ISSUE((R) + DEPTH) }                \
            }                                                                   \
        }
        STEPX(0, 4)  STEPX(1, 4)  STEPX(2, 4)  STEPX(3, 4)
        STEPX(4, 4)  STEPX(5, 4)  STEPX(6, 4)  STEPX(7, 4)
        STEPX(8, 4)  STEPX(9, 4)  STEPX(10, 4) STEPX(11, 4)
        STEPX(12, 4) STEPX(13, 2) STEPX(14, 0) STEPX(15, 0)
        #undef STEPX
        #undef ISSUE
        #undef SLOT
    } else {
        // ---- tail block (48 cells): simple compiler-managed stream ----
        const int n4 = (ncells * CH) >> 2;           // 1020
        const fx4* cv4 = (const fx4*)cvb;
        const fx4* lb4 = (const fx4*)lbb;
        for (int u = tid; u < n4; u += BLK) {
            const fx4 cc = cv4[u];
            const fx4 lc = lb4[u];
            const unsigned e0 = 4u * (unsigned)u;
            const unsigned c0 = e0 / 85u;
            const unsigned r0 = e0 - 85u * c0;
            const float rsp = s_resp[c0];
            const float cxx[4] = {cc.x, cc.y, cc.z, cc.w};
            const float lxx[4] = {lc.x, lc.y, lc.z, lc.w};
            float s_ = 0.f;
            #pragma unroll
            for (int k = 0; k < 4; ++k) {
                const unsigned rr = r0 + (unsigned)k;
                const float bv = bcef(cxx[k], lxx[k]);
                s_ += ((rr - 5u) < 80u) ? bv : 0.f;
                if (rr < 5u)        { s_ch[c0][rr] = cxx[k];  s_lh[c0][rr] = lxx[k]; }
                else if (rr >= 85u) { s_ch[c0 + 1][rr - 85u] = cxx[k];
                                      s_lh[c0 + 1][rr - 85u] = lxx[k]; }
            }
            p_sum = __builtin_fmaf(rsp, s_, p_sum);
        }
    }
    __syncthreads();   // headers visible to all waves

    // ---- geo phase: giou_loss + conf_loss, purely from LDS ----
    float g_sum = 0.f, c_sum = 0.f;
    if (tid < ncells) {
        const int t_  = base_cell + tid;
        const int i   = t_ / (S * A);
        const int rem = t_ - i * (S * A);
        const int j   = rem / A;
        const int a   = rem - j * A;
        const float aw = (a == 0) ? 12.f : ((a == 1) ? 19.f : 40.f);
        const float ah = (a == 0) ? 16.f : ((a == 1) ? 36.f : 28.f);

        const float dx = s_ch[tid][0], dy = s_ch[tid][1], dw = s_ch[tid][2],
                    dh = s_ch[tid][3], rcv = s_ch[tid][4];
        const float lxc = s_lh[tid][0], lyc = s_lh[tid][1], lwc = s_lh[tid][2],
                    lhc = s_lh[tid][3], resp = s_lh[tid][4];

        const float px = (sigmoidf_(dx) * 1.2f - 0.1f + (float)j) * 8.f;
        const float py = (sigmoidf_(dy) * 1.2f - 0.1f + (float)i) * 8.f;
        const float pw = __expf(dw) * aw;
        const float ph = __expf(dh) * ah;
        const float pconf = sigmoidf_(rcv);

        const float px1 = px - pw * 0.5f, py1 = py - ph * 0.5f;
        const float px2 = px + pw * 0.5f, py2 = py + ph * 0.5f;
        const float areap = pw * ph;

        // max_iou<0.5  <=>  max_k(3*inter_k - area_k) < area_p (division-free)
        const float px1_3 = 3.f * px1, px2_3 = 3.f * px2;
        float maxv = -1e30f;
        #pragma unroll 5
        for (int k = 0; k < MAXGT; ++k) {
            const fx4 bx = s_box[k];
            const float ba  = s_ba[k];
            const float kiw3 = fmaxf(fminf(px2_3, bx.z) - fmaxf(px1_3, bx.x), 0.f);
            const float kih  = fmaxf(fminf(py2, bx.w) - fmaxf(py1, bx.y), 0.f);
            maxv = fmaxf(maxv, __builtin_fmaf(kiw3, kih, -ba));
        }

        const float lx1 = lxc - lwc * 0.5f, ly1 = lyc - lhc * 0.5f;
        const float lx2 = lxc + lwc * 0.5f, ly2 = lyc + lhc * 0.5f;
        const float areal = lwc * lhc;
        const float iw = fmaxf(fminf(px2, lx2) - fmaxf(px1, lx1), 0.f);
        const float ih = fmaxf(fminf(py2, ly2) - fmaxf(py1, ly1), 0.f);
        const float inter = iw * ih;
        const float uni = areap + areal - inter;
        const float iou = inter * frcp(uni);
        const float ew = fmaxf(fmaxf(px2, lx2) - fminf(px1, lx1), 0.f);
        const float eh = fmaxf(fmaxf(py2, ly2) - fminf(py1, ly1), 0.f);
        const float enc = ew * eh;
        const float giou = iou - (enc - uni) * frcp(enc);
        g_sum = resp * (2.f - areal * (1.f / (608.f * 608.f))) * (1.f - giou);

        const float bgd = (1.f - resp) * ((maxv < areap) ? 1.f : 0.f);
        const float focal = (resp - pconf) * (resp - pconf);
        c_sum = focal * (resp + bgd) * bcef(rcv, resp);
    }

    // ---- block reduction (3 values) ----
    for (int off = 32; off > 0; off >>= 1) {
        g_sum += __shfl_down(g_sum, off, 64);
        c_sum += __shfl_down(c_sum, off, 64);
        p_sum += __shfl_down(p_sum, off, 64);
    }
    if (lane == 0) { sred[0][w] = g_sum; sred[1][w] = c_sum; sred[2][w] = p_sum; }
    __syncthreads();
    if (tid == 0) {
        float G = 0.f, C = 0.f, P = 0.f;
        #pragma unroll
        for (int q = 0; q < WPB; ++q) { G += sred[0][q]; C += sred[1][q]; P += sred[2][q]; }
        const int bid = blockIdx.y * gridDim.x + blockIdx.x;
        part[bid * 3 + 0] = G;
        part[bid * 3 + 1] = C;
        part[bid * 3 + 2] = P;
    }
}

// ---------------- final deterministic reduce ----------------
__global__ __launch_bounds__(256) void final_reduce(
    const float* __restrict__ part, float* __restrict__ out, int nblocks, float invB)
{
    const int tid = threadIdx.x;
    float g = 0.f, c = 0.f, p = 0.f;
    for (int k = tid; k < nblocks; k += 256) {
        g += part[3 * k + 0];
        c += part[3 * k + 1];
        p += part[3 * k + 2];
    }
    for (int off = 32; off > 0; off >>= 1) {
        g += __shfl_down(g, off, 64);
        c += __shfl_down(c, off, 64);
        p += __shfl_down(p, off, 64);
    }
    __shared__ float sred[3][4];
    const int lane = tid & 63, wv = tid >> 6;
    if (lane == 0) { sred[0][wv] = g; sred[1][wv] = c; sred[2][wv] = p; }
    __syncthreads();
    if (tid == 0) {
        float G = 0.f, C = 0.f, P = 0.f;
        #pragma unroll
        for (int q = 0; q < 4; ++q) { G += sred[0][q]; C += sred[1][q]; P += sred[2][q]; }
        out[0] = G * invB;
        out[1] = C * invB;
        out[2] = P * invB;
    }
}

extern "C" void kernel_launch(void* const* d_in, const int* in_sizes, int n_in,
                              void* d_out, int out_size, void* d_ws, size_t ws_size,
                              hipStream_t stream) {
    const float* conv   = (const float*)d_in[0];
    const float* label  = (const float*)d_in[1];
    const float* bboxes = (const float*)d_in[2];
    float* out  = (float*)d_out;
    float* part = (float*)d_ws;          // NBLK*3 = 4368 floats

    dim3 grid(GX, BATCH);
    yolo_unified_kernel<<<grid, BLK, 0, stream>>>(conv, label, bboxes, part);
    final_reduce<<<1, 256, 0, stream>>>(part, out, NBLK, 1.f / (float)BATCH);
}

// Round 13
// 52.649 us; speedup vs baseline: 1.5545x; 1.5545x over previous
//
#include <hip/hip_runtime.h>
#include <math.h>

#define S 76
#define A 3
#define CH 85            // 5 + 80
#define MAXGT 150
#define CPB (S * S * A)              // 17328 cells per batch
#define FPB (CPB * CH)               // 1472880 floats per batch
#define BATCH 16
#define TOTF4 ((BATCH * FPB) / 4)    // 5,891,520 float4s total
#define BLK 256
#define WPB (BLK / 64)               // 4 waves per block
#define ROUNDS 16                    // rounds per wave (64 f4 each)
#define DEPTH 4                      // LDS ring slots (DMA pipeline depth)
#define SPAN (BLK * ROUNDS)          // 4096 f4 per stream block
#define STREAM_BLOCKS ((TOTF4 + SPAN - 1) / SPAN)   // 1439
#define ATILE 128
#define AGX ((CPB + ATILE - 1) / ATILE)             // 136
#define GEO_BLOCKS (AGX * BATCH)                    // 2176
#define TOT_BLOCKS (STREAM_BLOCKS + GEO_BLOCKS)     // 3615
#define MAXC 200                     // cells spanned by one stream block (<=194)

typedef float fx4 __attribute__((ext_vector_type(4)));

__device__ __forceinline__ float frcp(float x) { return __builtin_amdgcn_rcpf(x); }
__device__ __forceinline__ float sigmoidf_(float x) { return frcp(1.f + __expf(-x)); }
// bce_with_logits(x,y) = ln(1+e^x) - x*y   (safe for |x| < ~80)
__device__ __forceinline__ float bcef(float x, float y) {
    const float t  = __builtin_amdgcn_exp2f(x * 1.44269504f);
    const float lg = __builtin_amdgcn_logf(1.f + t);            // log2(1+e^x)
    return __builtin_fmaf(0.69314718f, lg, -x * y);
}

// counted vmem wait; "memory" clobber orders all memory ops (ds_read, DMA issue)
template<int N>
__device__ __forceinline__ void vmwait() {
    asm volatile("s_waitcnt vmcnt(%0)" :: "i"(N) : "memory");
    __builtin_amdgcn_sched_barrier(0);
}
// direct global->LDS DMA, 16B per lane. LDS dest = wave-uniform base + lane*16.
__device__ __forceinline__ void gl_lds16(const float* g, void* l) {
    __builtin_amdgcn_global_load_lds(
        (const __attribute__((address_space(1))) void*)g,
        (__attribute__((address_space(3))) void*)l, 16, 0, 0);
}

// ---------------- fused kernel: block-role specialization ----------------
__global__ __launch_bounds__(BLK) void yolo_fused_kernel(
    const float* __restrict__ conv, const float* __restrict__ label,
    const float* __restrict__ bboxes, float* __restrict__ partA /*geo*/,
    float* __restrict__ partB /*stream*/)
{
    // smem union: stream = c-ring(16384) + l-ring(16384) + resp(800) + sredp(16)
    //             geo    = box(2400) + ba(600) + sred2(32)
    __shared__ __align__(16) char smem[33584];

    const unsigned bid = blockIdx.x;
    const int tid  = threadIdx.x;
    const int w    = tid >> 6;
    const int lane = tid & 63;
    // Bresenham role interleave: geo blocks evenly mixed among stream blocks.
    const unsigned geo_before = (unsigned)(((unsigned long long)bid * GEO_BLOCKS) / TOT_BLOCKS);
    const unsigned geo_after  = (unsigned)(((unsigned long long)(bid + 1) * GEO_BLOCKS) / TOT_BLOCKS);

    if (geo_after == geo_before) {
        // ================= STREAM role: prob_loss =================
        fx4*   lds_c  = (fx4*)smem;                    // [(w*DEPTH+slot)*64 + lane]
        fx4*   lds_l  = (fx4*)(smem + 16384);
        float* s_resp = (float*)(smem + 32768);
        float* sredp  = (float*)(smem + 33568);

        const unsigned sidx = bid - geo_before;
        const int base4 = (int)sidx * SPAN;            // block's first float4
        float p_sum = 0.f;

        if (sidx + 1 < STREAM_BLOCKS) {
            // ---- phase 0: resp for all touched cells -> LDS (drained at barrier,
            // so NO compiler vmem pollutes the counted region below) ----
            const unsigned base_e = 4u * (unsigned)base4;
            const unsigned cstart = base_e / 85u;
            const unsigned cend   = (base_e + SPAN * 4u - 1u) / 85u;
            const int nc = (int)(cend - cstart) + 1;   // <= 194
            for (int i2 = tid; i2 < nc; i2 += BLK)
                s_resp[i2] = label[(size_t)(cstart + i2) * CH + 4];
            __syncthreads();                            // vmcnt drains to 0 here

            // per-wave contiguous range: wave w owns [base4 + w*1024, +1024)
            const float* pc = conv  + ((size_t)base4 + (size_t)w * (ROUNDS * 64) + (size_t)lane) * 4;
            const float* pl = label + ((size_t)base4 + (size_t)w * (ROUNDS * 64) + (size_t)lane) * 4;

            #define SLOT(R) ((w * DEPTH + ((R) & 3)) * 64)
            #define ISSUE(R)                                                       \
                gl_lds16(pc + (size_t)(R) * 256, &lds_c[SLOT(R)]);                 \
                gl_lds16(pl + (size_t)(R) * 256, &lds_l[SLOT(R)]);

            // prologue: 4 rounds (8 loads) in flight; prime ping regs with slot 0
            ISSUE(0) ISSUE(1) ISSUE(2) ISSUE(3)
            fx4 rc[2], rl[2];
            vmwait<6>();                                // slot 0 DMA complete
            rc[0] = lds_c[SLOT(0) + lane];
            rl[0] = lds_l[SLOT(0) + lane];
            __builtin_amdgcn_sched_barrier(0);

            // round R: vmwait -> prefetch ds_read of slot R+1 (pong) ->
            // lgkmcnt(2) (ping reads retired; slot R safe to overwrite) ->
            // DMA refill slot R -> compute round R from ping regs.
            #define STEPX(R, W)                                                     \
            {                                                                       \
                if ((R) + 1 < ROUNDS) {                                             \
                    vmwait<W>();                                                    \
                    rc[((R) + 1) & 1] = lds_c[SLOT((R) + 1) + lane];                \
                    rl[((R) + 1) & 1] = lds_l[SLOT((R) + 1) + lane];                \
                    __builtin_amdgcn_sched_barrier(0);                              \
                }                                                                   \
                if ((R) + DEPTH < ROUNDS) {                                         \
                    asm volatile("s_waitcnt lgkmcnt(2)" ::: "memory");              \
                    __builtin_amdgcn_sched_barrier(0);                              \
                    ISSUE((R) + DEPTH)                                              \
                }                                                                   \
                {                                                                   \
                    const fx4 cc = rc[(R) & 1];                                     \
                    const fx4 lc = rl[(R) & 1];                                     \
                    const unsigned e0 = 4u * (unsigned)(base4 + w * (ROUNDS * 64) + (R) * 64 + lane); \
                    const unsigned c0 = e0 / 85u;                                   \
                    const unsigned r0 = e0 - 85u * c0;                              \
                    const float rsp = s_resp[c0 - cstart];                          \
                    const float cxx[4] = {cc.x, cc.y, cc.z, cc.w};                  \
                    const float lxx[4] = {lc.x, lc.y, lc.z, lc.w};                  \
                    float s_ = 0.f;                                                 \
                    _Pragma("unroll")                                               \
                    for (int k = 0; k < 4; ++k) {                                   \
                        const unsigned rr = r0 + (unsigned)k;                       \
                        const float bv = bcef(cxx[k], lxx[k]);                      \
                        s_ += ((rr - 5u) < 80u) ? bv : 0.f;                         \
                    }                                                               \
                    p_sum = __builtin_fmaf(rsp, s_, p_sum);                         \
                }                                                                   \
            }
            STEPX(0, 4)  STEPX(1, 4)  STEPX(2, 4)  STEPX(3, 4)
            STEPX(4, 4)  STEPX(5, 4)  STEPX(6, 4)  STEPX(7, 4)
            STEPX(8, 4)  STEPX(9, 4)  STEPX(10, 4) STEPX(11, 4)
            STEPX(12, 4) STEPX(13, 2) STEPX(14, 0) STEPX(15, 0)
            #undef STEPX
            #undef ISSUE
            #undef SLOT
        } else {
            // ---- tail path: clamped, compiler-managed (only the last block) ----
            const float4* cv4 = (const float4*)conv;
            const float4* lb4 = (const float4*)label;
            for (int r = 0; r < ROUNDS; ++r) {
                const int u = base4 + r * BLK + tid;
                if (u >= TOTF4) break;
                const float4 cc = cv4[(size_t)u];
                const float4 lc = lb4[(size_t)u];
                const unsigned e0 = 4u * (unsigned)u;
                const unsigned c0 = e0 / 85u;
                const unsigned r0c = e0 - 85u * c0;
                const float rspc = label[(size_t)c0 * CH + 4];
                const float cxx[4] = {cc.x, cc.y, cc.z, cc.w};
                const float lxx[4] = {lc.x, lc.y, lc.z, lc.w};
                float s_ = 0.f;
                #pragma unroll
                for (int k = 0; k < 4; ++k) {
                    const unsigned rr = r0c + k;
                    const float bv = bcef(cxx[k], lxx[k]);
                    s_ += ((rr - 5u) < 80u) ? bv : 0.f;
                }
                p_sum = __builtin_fmaf(rspc, s_, p_sum);
            }
        }

        for (int off = 32; off > 0; off >>= 1) p_sum += __shfl_down(p_sum, off, 64);
        if (lane == 0) sredp[w] = p_sum;
        __syncthreads();
        if (tid == 0) {
            float P = 0.f;
            #pragma unroll
            for (int q = 0; q < WPB; ++q) P += sredp[q];
            partB[sidx] = P;
        }
    } else {
        // ================= GEO role: giou_loss + conf_loss =================
        fx4*   s_box  = (fx4*)smem;          // 3*x1, y1, 3*x2, y2
        float* s_ba   = (float*)(smem + 2400);
        float* sred2  = (float*)(smem + 3000);   // [2][WPB]

        const unsigned gidx = geo_before;
        const int b    = gidx / AGX;
        const int tile = gidx - b * AGX;

        const int ci = tid >> 1;
        const int pr = tid & 1;
        const int t = tile * ATILE + ci;
        const bool valid = (t < CPB);
        const int tc = valid ? t : (CPB - 1);

        const size_t boff = (size_t)b * FPB;
        const float* cv = conv  + boff + (size_t)tc * CH;
        const float* lb = label + boff + (size_t)tc * CH;

        if (tid < MAXGT) {
            const float4 bx = *(const float4*)(bboxes + (size_t)b * (MAXGT * 4) + tid * 4);
            const float hw = bx.z * 0.5f, hh = bx.w * 0.5f;
            fx4 v; v.x = 3.f * (bx.x - hw); v.y = bx.y - hh;
            v.z = 3.f * (bx.x + hw); v.w = bx.y + hh;
            s_box[tid] = v;
            s_ba[tid]  = bx.z * bx.w;
        }
        const float dx = cv[0], dy = cv[1], dw = cv[2], dh = cv[3], rc = cv[4];
        const float lx = lb[0], ly = lb[1], lw = lb[2], lh = lb[3], resp = lb[4];
        __syncthreads();

        const int i   = tc / (S * A);
        const int rem = tc - i * (S * A);
        const int j   = rem / A;
        const int a   = rem - j * A;
        const float aw = (a == 0) ? 12.f : ((a == 1) ? 19.f : 40.f);
        const float ah = (a == 0) ? 16.f : ((a == 1) ? 36.f : 28.f);

        const float px = (sigmoidf_(dx) * 1.2f - 0.1f + (float)j) * 8.f;
        const float py = (sigmoidf_(dy) * 1.2f - 0.1f + (float)i) * 8.f;
        const float pw = __expf(dw) * aw;
        const float ph = __expf(dh) * ah;
        const float pconf = sigmoidf_(rc);

        const float px1 = px - pw * 0.5f, py1 = py - ph * 0.5f;
        const float px2 = px + pw * 0.5f, py2 = py + ph * 0.5f;
        const float areap = pw * ph;

        // max_iou<0.5  <=>  max_k(3*inter_k - area_k) < area_p  (division-free)
        const float px1_3 = 3.f * px1, px2_3 = 3.f * px2;
        float maxv = -1e30f;
        #pragma unroll 5
        for (int k = pr; k < MAXGT; k += 2) {
            const fx4 bx = s_box[k];
            const float ba  = s_ba[k];
            const float kiw3 = fmaxf(fminf(px2_3, bx.z) - fmaxf(px1_3, bx.x), 0.f);
            const float kih  = fmaxf(fminf(py2, bx.w) - fmaxf(py1, bx.y), 0.f);
            maxv = fmaxf(maxv, __builtin_fmaf(kiw3, kih, -ba));
        }
        maxv = fmaxf(maxv, __shfl_xor(maxv, 1, 64));

        float g_sum = 0.f, c_sum = 0.f;
        if (pr == 0 && valid) {
            const float lx1 = lx - lw * 0.5f, ly1 = ly - lh * 0.5f;
            const float lx2 = lx + lw * 0.5f, ly2 = ly + lh * 0.5f;
            const float areal = lw * lh;
            const float iw = fmaxf(fminf(px2, lx2) - fmaxf(px1, lx1), 0.f);
            const float ih = fmaxf(fminf(py2, ly2) - fmaxf(py1, ly1), 0.f);
            const float inter = iw * ih;
            const float uni = areap + areal - inter;
            const float iou = inter * frcp(uni);
            const float ew = fmaxf(fmaxf(px2, lx2) - fminf(px1, lx1), 0.f);
            const float eh = fmaxf(fmaxf(py2, ly2) - fminf(py1, ly1), 0.f);
            const float enc = ew * eh;
            const float giou = iou - (enc - uni) * frcp(enc);
            g_sum = resp * (2.f - areal * (1.f / (608.f * 608.f))) * (1.f - giou);

            const float bgd = (1.f - resp) * ((maxv < areap) ? 1.f : 0.f);
            const float focal = (resp - pconf) * (resp - pconf);
            c_sum = focal * (resp + bgd) * bcef(rc, resp);
        }

        for (int off = 32; off > 0; off >>= 1) {
            g_sum += __shfl_down(g_sum, off, 64);
            c_sum += __shfl_down(c_sum, off, 64);
        }
        if (lane == 0) { sred2[0 * WPB + w] = g_sum; sred2[1 * WPB + w] = c_sum; }
        __syncthreads();
        if (tid == 0) {
            float G = 0.f, C = 0.f;
            #pragma unroll
            for (int q = 0; q < WPB; ++q) { G += sred2[q]; C += sred2[WPB + q]; }
            partA[gidx * 2 + 0] = G;
            partA[gidx * 2 + 1] = C;
        }
    }
}

// ---------------- final deterministic reduce ----------------
__global__ __launch_bounds__(256) void final_reduce(
    const float* __restrict__ partA, const float* __restrict__ partB,
    float* __restrict__ out, int nA, int nB, float invB)
{
    const int tid = threadIdx.x;
    float g = 0.f, c = 0.f, p = 0.f;
    for (int k = tid; k < nA; k += 256) { g += partA[2 * k]; c += partA[2 * k + 1]; }
    for (int k = tid; k < nB; k += 256) p += partB[k];
    for (int off = 32; off > 0; off >>= 1) {
        g += __shfl_down(g, off, 64);
        c += __shfl_down(c, off, 64);
        p += __shfl_down(p, off, 64);
    }
    __shared__ float sred[3][4];
    const int lane = tid & 63, wv = tid >> 6;
    if (lane == 0) { sred[0][wv] = g; sred[1][wv] = c; sred[2][wv] = p; }
    __syncthreads();
    if (tid == 0) {
        float G = 0.f, C = 0.f, P = 0.f;
        #pragma unroll
        for (int q = 0; q < 4; ++q) { G += sred[0][q]; C += sred[1][q]; P += sred[2][q]; }
        out[0] = G * invB;
        out[1] = C * invB;
        out[2] = P * invB;
    }
}

extern "C" void kernel_launch(void* const* d_in, const int* in_sizes, int n_in,
                              void* d_out, int out_size, void* d_ws, size_t ws_size,
                              hipStream_t stream) {
    const float* conv   = (const float*)d_in[0];
    const float* label  = (const float*)d_in[1];
    const float* bboxes = (const float*)d_in[2];
    float* out  = (float*)d_out;
    float* wsf  = (float*)d_ws;
    float* partA = wsf;                 // GEO_BLOCKS*2 = 4352 floats
    float* partB = wsf + 8192;          // STREAM_BLOCKS = 1439 floats

    yolo_fused_kernel<<<TOT_BLOCKS, BLK, 0, stream>>>(conv, label, bboxes, partA, partB);
    final_reduce<<<1, 256, 0, stream>>>(partA, partB, out, GEO_BLOCKS, STREAM_BLOCKS,
                                        1.f / (float)BATCH);
}